// Round 1
// 4466.164 us; speedup vs baseline: 1.4334x; 1.4334x over previous
//
#include <hip/hip_runtime.h>
#include <math.h>

typedef unsigned short u16;
typedef unsigned int u32;

typedef short bf16x8 __attribute__((ext_vector_type(8)));
typedef unsigned short u16x8 __attribute__((ext_vector_type(8)));
typedef float f32x4 __attribute__((ext_vector_type(4)));
typedef __attribute__((address_space(1))) const void gconst_t;
typedef __attribute__((address_space(3))) void lds_t;

__device__ __forceinline__ float bf2f(u16 u) {
  union { u32 i; float f; } v; v.i = ((u32)u) << 16; return v.f;
}
__device__ __forceinline__ u16 f2bf(float f) {
  union { float f; u32 i; } v; v.f = f;
  u32 r = v.i + 0x7fffu + ((v.i >> 16) & 1u);   // RNE
  return (u16)(r >> 16);
}

// ---------------------------------------------------------------------------
// Row LayerNorm over D=1280, block=320 threads (5 waves), one row per block.
// ---------------------------------------------------------------------------
__device__ __forceinline__ void store4(float* p, float4 y) { *(float4*)p = y; }
__device__ __forceinline__ void store4(u16* p, float4 y) {
  ushort4 u; u.x = f2bf(y.x); u.y = f2bf(y.y); u.z = f2bf(y.z); u.w = f2bf(y.w);
  *(ushort4*)p = u;
}

template <typename OutT>
__global__ __launch_bounds__(320) void ln_rows(const float* __restrict__ in,
    OutT* __restrict__ out, const float* __restrict__ w, const float* __restrict__ b)
{
  __shared__ float ps[5], pss[5];
  const int row = blockIdx.x, t = threadIdx.x;
  const float4 x = ((const float4*)(in + (size_t)row * 1280))[t];
  float s = x.x + x.y + x.z + x.w;
  float ss = x.x * x.x + x.y * x.y + x.z * x.z + x.w * x.w;
#pragma unroll
  for (int o = 32; o > 0; o >>= 1) { s += __shfl_xor(s, o); ss += __shfl_xor(ss, o); }
  if ((t & 63) == 0) { ps[t >> 6] = s; pss[t >> 6] = ss; }
  __syncthreads();
  s = ps[0] + ps[1] + ps[2] + ps[3] + ps[4];
  ss = pss[0] + pss[1] + pss[2] + pss[3] + pss[4];
  const float mean = s * (1.f / 1280.f);
  const float rstd = rsqrtf(ss * (1.f / 1280.f) - mean * mean + 1e-5f);
  float4 y;
  y.x = (x.x - mean) * rstd; y.y = (x.y - mean) * rstd;
  y.z = (x.z - mean) * rstd; y.w = (x.w - mean) * rstd;
  if (w) {
    const float4 wv4 = ((const float4*)w)[t];
    const float4 bv4 = ((const float4*)b)[t];
    y.x = y.x * wv4.x + bv4.x; y.y = y.y * wv4.y + bv4.y;
    y.z = y.z * wv4.z + bv4.z; y.w = y.w * wv4.w + bv4.w;
  }
  store4(out + (size_t)row * 1280 + t * 4, y);
}

// lat[r][:] = latents[r & 63][:]
__global__ __launch_bounds__(320) void lat_init(const float* __restrict__ latents,
                                                float* __restrict__ lat)
{
  const int r = blockIdx.x, t = threadIdx.x;
  ((float4*)(lat + (size_t)r * 1280))[t] =
      ((const float4*)(latents + (size_t)(r & 63) * 1280))[t];
}

// dst[n][k] = src[k][n] * (fold ? fold[k] : 1), cast to bf16. 32x32 LDS tiles.
__global__ __launch_bounds__(256) void transcast(const float* __restrict__ src,
    u16* __restrict__ dst, const float* __restrict__ fold, int K, int N)
{
  __shared__ float tile[32][33];
  const int n0 = blockIdx.x * 32, k0 = blockIdx.y * 32;
  const int tx = threadIdx.x & 31, ty = threadIdx.x >> 5;
#pragma unroll
  for (int r = ty; r < 32; r += 8) {
    float v = src[(size_t)(k0 + r) * N + n0 + tx];
    if (fold) v *= fold[k0 + r];
    tile[r][tx] = v;
  }
  __syncthreads();
#pragma unroll
  for (int r = ty; r < 32; r += 8)
    dst[(size_t)(n0 + r) * K + k0 + tx] = f2bf(tile[tx][r]);
}

// out[h] = sum_d bvec[d] * wT[h][d]   (wT bf16 [N][K])
__global__ __launch_bounds__(64) void bias_dot(const u16* __restrict__ wT,
    const float* __restrict__ bvec, float* __restrict__ outp, int K)
{
  const int h = blockIdx.x, lane = threadIdx.x;
  const u16* row = wT + (size_t)h * K;
  float s = 0.f;
  for (int i = lane; i < K; i += 64) s += bvec[i] * bf2f(row[i]);
#pragma unroll
  for (int o = 32; o > 0; o >>= 1) s += __shfl_xor(s, o);
  if (lane == 0) outp[h] = s;
}

// ---------------------------------------------------------------------------
// In-place LayerNorm over contiguous 96-element segments (q/k head-dim LN).
// ---------------------------------------------------------------------------
__global__ __launch_bounds__(256) void seg_ln(u16* __restrict__ buf,
    const float* __restrict__ w, const float* __restrict__ b, float scale, int nseg)
{
  const int seg = blockIdx.x * 4 + (threadIdx.x >> 6);
  if (seg >= nseg) return;
  const int lane = threadIdx.x & 63;
  u16* p = buf + (size_t)seg * 96;
  const float a = bf2f(p[lane]);
  const float c = (lane < 32) ? bf2f(p[64 + lane]) : 0.f;
  float s = a + c, ss = a * a + c * c;
#pragma unroll
  for (int o = 32; o > 0; o >>= 1) { s += __shfl_xor(s, o); ss += __shfl_xor(ss, o); }
  const float mean = s * (1.f / 96.f);
  const float rstd = rsqrtf(ss * (1.f / 96.f) - mean * mean + 1e-5f);
  p[lane] = f2bf(((a - mean) * rstd * w[lane] + b[lane]) * scale);
  if (lane < 32)
    p[64 + lane] = f2bf(((c - mean) * rstd * w[64 + lane] + b[64 + lane]) * scale);
}

// ---------------------------------------------------------------------------
// bf16 MFMA GEMM, m97 pattern (kept for the small GEMMs).
// flags: 1 = bf16 out, 2 = relu, 4 = column split at ldc (C0 then C1).
// out_row = (in_row >> sh)*bstride + off + (in_row & ((1<<sh)-1))
// ---------------------------------------------------------------------------
#define GTM 128
#define GTN 128
#define GBK 64

__global__ __launch_bounds__(256) void gemm_bf16(
    const u16* __restrict__ A, const u16* __restrict__ BT,
    void* C0, void* C1, const float* __restrict__ bias, const float* resid,
    int M, int N, int ldc, int K, int sh, int bstride, int off, int flags)
{
  __shared__ __align__(16) u16 As[GTM * GBK];
  __shared__ __align__(16) u16 Bs[GTN * GBK];
  const int tid = threadIdx.x;
  const int lane = tid & 63;
  const int wv = tid >> 6;
  const int m0 = blockIdx.y * GTM;
  const int n0 = blockIdx.x * GTN;
  const int wm = (wv >> 1) * 64;
  const int wn = (wv & 1) * 64;
  const int srow = lane >> 3;
  const int scol = (lane & 7) * 8;

  f32x4 acc[4][4] = {};

  const u16* Ab = A + (size_t)m0 * K;
  const u16* Bb = BT + (size_t)n0 * K;

  for (int kt = 0; kt < K; kt += GBK) {
#pragma unroll
    for (int it = 0; it < 4; ++it) {
      const int r = wv * 32 + it * 8;
      const u16* ga = Ab + (size_t)(r + srow) * K + kt + scol;
      __builtin_amdgcn_global_load_lds((gconst_t*)ga, (lds_t*)(As + r * GBK), 16, 0, 0);
      const u16* gb = Bb + (size_t)(r + srow) * K + kt + scol;
      __builtin_amdgcn_global_load_lds((gconst_t*)gb, (lds_t*)(Bs + r * GBK), 16, 0, 0);
    }
    __syncthreads();
#pragma unroll
    for (int ks = 0; ks < GBK; ks += 32) {
      bf16x8 af[4], bfr[4];
      const int koff = ks + ((lane >> 4) << 3);
      const int rsel = lane & 15;
#pragma unroll
      for (int f = 0; f < 4; ++f)
        af[f] = *(const bf16x8*)(As + (wm + f * 16 + rsel) * GBK + koff);
#pragma unroll
      for (int f = 0; f < 4; ++f)
        bfr[f] = *(const bf16x8*)(Bs + (wn + f * 16 + rsel) * GBK + koff);
#pragma unroll
      for (int fm = 0; fm < 4; ++fm)
#pragma unroll
        for (int fn = 0; fn < 4; ++fn)
          acc[fm][fn] = __builtin_amdgcn_mfma_f32_16x16x32_bf16(
              af[fm], bfr[fn], acc[fm][fn], 0, 0, 0);
    }
    __syncthreads();
  }

  const int colb = n0 + wn + (lane & 15);
  const int rowb = m0 + wm + ((lane >> 4) << 2);
  const int msk = (1 << sh) - 1;
  const bool obf = flags & 1;
  const bool rel = flags & 2;
  const bool spl = flags & 4;
#pragma unroll
  for (int fm = 0; fm < 4; ++fm) {
#pragma unroll
    for (int r = 0; r < 4; ++r) {
      const int ir = rowb + fm * 16 + r;
      const size_t orow = (size_t)((ir >> sh) * bstride + off + (ir & msk));
#pragma unroll
      for (int fn = 0; fn < 4; ++fn) {
        const int col = colb + fn * 16;
        float v = acc[fm][fn][r];
        if (bias) v += bias[col];
        if (rel) v = fmaxf(v, 0.f);
        void* cp = C0;
        int cl = col;
        if (spl && col >= ldc) { cp = C1; cl = col - ldc; }
        const size_t idx = orow * (size_t)ldc + cl;
        if (resid) v += resid[idx];
        if (obf) ((u16*)cp)[idx] = f2bf(v);
        else ((float*)cp)[idx] = v;
      }
    }
  }
}

// ---------------------------------------------------------------------------
// 256x256-tile, BK=64, 8-wave, 8-phase bf16 GEMM (learn_hip m201 schedule,
// T1+T2+T3/T4+T5) specialized for the ctx K/V projection:
//   C[M,N] = A[M,K] @ BT[N,K]^T + bias, bf16 out, column split at ldc,
//   out_row = (in_row >> sh)*bstride + off + (in_row & ((1<<sh)-1)).
// Requires: M%256==0, N%256==0, K%64==0, K/64 >= 2, grid = (M/256)*(N/256),
//           grid%8==0, ldc%256==0 (so each block is entirely K or entirely V).
//
// LDS layout: As/Bs[buf][kk][row][32cols] (kk = K half of the 64-wide tile).
//   - each 16KiB (mat,kk) "half-tile" is contiguous -> global_load_lds can
//     stage it linearly (wave-uniform base + lane*16) [m104 constraint]
//   - phases 0/1 consume kk=0, phases 2/3 consume kk=1 -> the counted
//     vmcnt(4) gate at phase 0/2 provably covers exactly the two half-tiles
//     those phases need (stage order A-k0, B-k0, A-k1, B-k1, 2 loads each).
//   - bank swizzle: 16B granule g stored at g ^ ((row>>1)&3); read side uses
//     the same XOR; global_load_lds source pre-applies the inverse (rule #21).
//     Within a 16-lane quad this yields 2-way (free) instead of 8-way.
// ---------------------------------------------------------------------------
__global__ __launch_bounds__(512, 2) void gemm_kv256(
    const u16* __restrict__ A, const u16* __restrict__ BT,
    u16* __restrict__ C0, u16* __restrict__ C1, const float* __restrict__ bias,
    int K, int ldc, int sh, int bstride, int off, int nbx)
{
  __shared__ __align__(16) u16 As[2][2][8192];   // [buf][kk][256*32]
  __shared__ __align__(16) u16 Bs[2][2][8192];   // 128 KiB total

  // T1: XCD-bijective block swizzle (grid % 8 == 0 guaranteed by caller)
  const int cpx = gridDim.x >> 3;
  int bid = blockIdx.x;
  bid = (bid & 7) * cpx + (bid >> 3);
  const int by = bid / nbx, bx = bid - by * nbx;

  const int tid = threadIdx.x, lane = tid & 63, wv = tid >> 6;
  const int quad = lane >> 4, rsel = lane & 15;
  const int wm = (wv >> 2) * 128, wn = (wv & 3) * 64;   // per-wave 128x64 output

  const u16* Ab = A + (size_t)(by * 256) * K;
  const u16* Bb = BT + (size_t)(bx * 256) * K;

  // staging constants: thread covers rows {srow, srow+128}, LDS granule lane&3.
  // (row>>1)&3 == (lane>>3)&3 for both rows (row = wv*16 + lane/4 (+128)).
  const int srow = wv * 16 + (lane >> 2);
  const int sgo  = (((lane & 3) ^ ((lane >> 3) & 3)) << 3);   // src elem offset
  // read constant: frag granule = quad, row base multiple of 16 ->
  // (row>>1)&3 == (rsel>>1)&3.
  const int gsw  = ((quad ^ ((rsel >> 1) & 3)) << 3);

  const int KT = K >> 6;
  f32x4 acc[8][4] = {};

  // stage one 16KiB half-tile: mat 0=A 1=B, kk = K half, of k-tile kt -> buf bsel
  auto stage = [&](int mat, int kk, int kt, int bsel) {
    const u16* g = mat ? Bb : Ab;
    u16* l = mat ? &Bs[bsel][kk][0] : &As[bsel][kk][0];
    const u16* s0 = g + (size_t)srow * K + kt * 64 + kk * 32 + sgo;
    __builtin_amdgcn_global_load_lds((gconst_t*)s0, (lds_t*)(l + tid * 8), 16, 0, 0);
    const u16* s1 = g + (size_t)(srow + 128) * K + kt * 64 + kk * 32 + sgo;
    __builtin_amdgcn_global_load_lds((gconst_t*)s1, (lds_t*)(l + 4096 + tid * 8), 16, 0, 0);
  };

  // prologue: tile 0 fully + tile 1 fully; drain to tile-0-complete only.
  stage(0, 0, 0, 0); stage(1, 0, 0, 0); stage(0, 1, 0, 0); stage(1, 1, 0, 0);
  stage(0, 0, 1, 1); stage(1, 0, 1, 1); stage(0, 1, 1, 1); stage(1, 1, 1, 1);
  asm volatile("s_waitcnt vmcnt(8)" ::: "memory");
  __builtin_amdgcn_s_barrier();
  asm volatile("" ::: "memory");

  for (int t = 0; t < KT; ++t) {
    const int c = t & 1;
    const u16* An = &As[c][0][0];
    const u16* Bn = &Bs[c][0][0];
    bf16x8 bb[4];                       // B frags live across phase pairs
#pragma unroll
    for (int p = 0; p < 4; ++p) {
      const int kk = p >> 1, rh = p & 1;
      // counted-vmcnt gate (T4): oldest 4 in-flight = the two half-tiles
      // phases p..p+1 consume. Never 0 except the final tile's k-hi gate.
      if (t > 0 && rh == 0) {
        if (p == 0 || t < KT - 1) asm volatile("s_waitcnt vmcnt(4)" ::: "memory");
        else                      asm volatile("s_waitcnt vmcnt(0)" ::: "memory");
        __builtin_amdgcn_s_barrier();
        asm volatile("" ::: "memory");
        __builtin_amdgcn_sched_barrier(0);
      }
      // ds reads: 4 A frags (+4 B frags on kk entry)
      bf16x8 af[4];
      const u16* Ap = An + kk * 8192 + (wm + rh * 64 + rsel) * 32 + gsw;
#pragma unroll
      for (int f = 0; f < 4; ++f) af[f] = *(const bf16x8*)(Ap + f * 512);
      if (rh == 0) {
        const u16* Bp = Bn + kk * 8192 + (wn + rsel) * 32 + gsw;
#pragma unroll
        for (int g = 0; g < 4; ++g) bb[g] = *(const bf16x8*)(Bp + g * 512);
      }
      // stage one half-tile of k-tile t+1 (order: A-k0, B-k0, A-k1, B-k1);
      // tile 1 was staged in the prologue, so tile 0 stages nothing.
      if (t >= 1 && t + 1 < KT) stage(p & 1, p >> 1, t + 1, (t + 1) & 1);
      __builtin_amdgcn_s_barrier();
      asm volatile("s_waitcnt lgkmcnt(0)" ::: "memory");
      __builtin_amdgcn_sched_barrier(0);           // rule #18
      __builtin_amdgcn_s_setprio(1);               // T5
#pragma unroll
      for (int f = 0; f < 4; ++f)
#pragma unroll
        for (int g = 0; g < 4; ++g)
          acc[rh * 4 + f][g] = __builtin_amdgcn_mfma_f32_16x16x32_bf16(
              af[f], bb[g], acc[rh * 4 + f][g], 0, 0, 0);
      __builtin_amdgcn_s_setprio(0);
      __builtin_amdgcn_s_barrier();
      asm volatile("" ::: "memory");
    }
  }

  // epilogue: bias + bf16 + K/V split (ldc%256==0 -> split is per-block uniform)
  const bool isv = (bx * 256) >= ldc;
  u16* Cb = isv ? C1 : C0;
  const int cb0 = bx * 256 - (isv ? ldc : 0);
  const int colb = cb0 + wn + rsel;
  const int bcol = bx * 256 + wn + rsel;
  const int rowb = by * 256 + wm + quad * 4;
  const int msk = (1 << sh) - 1;
#pragma unroll
  for (int fm = 0; fm < 8; ++fm) {
#pragma unroll
    for (int r = 0; r < 4; ++r) {
      const int ir = rowb + fm * 16 + r;
      const size_t orow = (size_t)((ir >> sh) * bstride + off + (ir & msk));
      u16* cp = Cb + orow * (size_t)ldc;
#pragma unroll
      for (int fn = 0; fn < 4; ++fn) {
        const float v = acc[fm][fn][r] + bias[bcol + fn * 16];
        cp[colb + fn * 16] = f2bf(v);
      }
    }
  }
}

// ---------------------------------------------------------------------------
// MFMA flash attention. One block per (h=blockIdx.x, b=blockIdx.y), 4 waves.
// ---------------------------------------------------------------------------
__global__ __launch_bounds__(256) void attn_mfma(
    const u16* __restrict__ Q, const u16* __restrict__ Kb,
    const u16* __restrict__ Vb, u16* __restrict__ Res)
{
  __shared__ __align__(16) u16 Ks[64 * 104];
  __shared__ __align__(16) u16 Vt[96 * 72];
  __shared__ __align__(16) u16 Ps[4][16 * 72];
  const int h = blockIdx.x, b = blockIdx.y;
  const int t = threadIdx.x, lane = t & 63, wv = t >> 6;
  const int quad = lane >> 4, rsel = lane & 15;

  bf16x8 aq[3];
  const int qrow0 = b * 64 + wv * 16;
  {
    const u16* qp = Q + (size_t)(qrow0 + rsel) * 1536 + h * 96 + quad * 8;
    aq[0] = *(const bf16x8*)(qp);
    aq[1] = *(const bf16x8*)(qp + 32);
    aq[2] = *(const bf16x8*)(qp + 64);
  }

  f32x4 accO[6] = {};
  float mrow[4] = {-1e30f, -1e30f, -1e30f, -1e30f};
  float lrow[4] = {0.f, 0.f, 0.f, 0.f};

  const size_t kvbase = (size_t)b * 2112 * 1536 + (size_t)h * 96;
  u16* ps = Ps[wv];

  for (int tile = 0; tile < 33; ++tile) {
    __syncthreads();
#pragma unroll
    for (int it = 0; it < 3; ++it) {
      const int e0 = (((wv * 3 + it) << 6) + lane) << 3;
      const int j = e0 / 96, d = e0 - j * 96;
      const u16x8 k8 = *(const u16x8*)(Kb + kvbase + (size_t)(tile * 64 + j) * 1536 + d);
      *(u16x8*)(Ks + j * 104 + d) = k8;
    }
#pragma unroll
    for (int it = 0; it < 3; ++it) {
      const int g = ((wv * 3 + it) << 6) + lane;
      const int kvp = g & 31, dr = g >> 5;
      const size_t ga = kvbase + (size_t)(tile * 64 + kvp * 2) * 1536 + dr * 4;
      const ushort4 va = *(const ushort4*)(Vb + ga);
      const ushort4 vb4 = *(const ushort4*)(Vb + ga + 1536);
      u32* vt = (u32*)Vt;
      vt[(dr * 4 + 0) * 36 + kvp] = (u32)va.x | ((u32)vb4.x << 16);
      vt[(dr * 4 + 1) * 36 + kvp] = (u32)va.y | ((u32)vb4.y << 16);
      vt[(dr * 4 + 2) * 36 + kvp] = (u32)va.z | ((u32)vb4.z << 16);
      vt[(dr * 4 + 3) * 36 + kvp] = (u32)va.w | ((u32)vb4.w << 16);
    }
    __syncthreads();

    f32x4 accS[4] = {};
#pragma unroll
    for (int nt = 0; nt < 4; ++nt) {
#pragma unroll
      for (int kt = 0; kt < 3; ++kt) {
        const bf16x8 bk = *(const bf16x8*)(Ks + (nt * 16 + rsel) * 104 + kt * 32 + quad * 8);
        accS[nt] = __builtin_amdgcn_mfma_f32_16x16x32_bf16(aq[kt], bk, accS[nt], 0, 0, 0);
      }
    }

    float alpha[4], rs[4];
#pragma unroll
    for (int r = 0; r < 4; ++r) {
      float mt = fmaxf(fmaxf(accS[0][r], accS[1][r]), fmaxf(accS[2][r], accS[3][r]));
      mt = fmaxf(mt, __shfl_xor(mt, 1));
      mt = fmaxf(mt, __shfl_xor(mt, 2));
      mt = fmaxf(mt, __shfl_xor(mt, 4));
      mt = fmaxf(mt, __shfl_xor(mt, 8));
      const float nm = fmaxf(mrow[r], mt);
      alpha[r] = __expf(mrow[r] - nm);
      mrow[r] = nm;
      rs[r] = 0.f;
    }
#pragma unroll
    for (int nt = 0; nt < 4; ++nt)
#pragma unroll
      for (int r = 0; r < 4; ++r) {
        const float p = __expf(accS[nt][r] - mrow[r]);
        accS[nt][r] = p;
        rs[r] += p;
      }
#pragma unroll
    for (int r = 0; r < 4; ++r) {
      rs[r] += __shfl_xor(rs[r], 1);
      rs[r] += __shfl_xor(rs[r], 2);
      rs[r] += __shfl_xor(rs[r], 4);
      rs[r] += __shfl_xor(rs[r], 8);
      lrow[r] = lrow[r] * alpha[r] + rs[r];
    }
#pragma unroll
    for (int nd = 0; nd < 6; ++nd)
#pragma unroll
      for (int r = 0; r < 4; ++r) accO[nd][r] *= alpha[r];

#pragma unroll
    for (int nt = 0; nt < 4; ++nt)
#pragma unroll
      for (int r = 0; r < 4; ++r)
        ps[(quad * 4 + r) * 72 + nt * 16 + rsel] = f2bf(accS[nt][r]);

#pragma unroll
    for (int kt = 0; kt < 2; ++kt) {
      const bf16x8 ap = *(const bf16x8*)(ps + rsel * 72 + kt * 32 + quad * 8);
#pragma unroll
      for (int nd = 0; nd < 6; ++nd) {
        const bf16x8 bv = *(const bf16x8*)(Vt + (nd * 16 + rsel) * 72 + kt * 32 + quad * 8);
        accO[nd] = __builtin_amdgcn_mfma_f32_16x16x32_bf16(ap, bv, accO[nd], 0, 0, 0);
      }
    }
  }

  float il[4];
#pragma unroll
  for (int r = 0; r < 4; ++r) il[r] = 1.f / lrow[r];
#pragma unroll
  for (int nd = 0; nd < 6; ++nd)
#pragma unroll
    for (int r = 0; r < 4; ++r)
      Res[(size_t)(qrow0 + quad * 4 + r) * 1536 + h * 96 + nd * 16 + rsel] =
          f2bf(accO[nd][r] * il[r]);
}

// ---------------------------------------------------------------------------
extern "C" void kernel_launch(void* const* d_in, const int* in_sizes, int n_in,
                              void* d_out, int out_size, void* d_ws, size_t ws_size,
                              hipStream_t stream) {
  const float* context  = (const float*)d_in[0];
  const float* latents  = (const float*)d_in[1];
  const float* ctx_ln_w = (const float*)d_in[2];
  const float* ctx_ln_b = (const float*)d_in[3];
  const float* lat_ln_w = (const float*)d_in[4];
  const float* lat_ln_b = (const float*)d_in[5];
  const float* q_ln_w   = (const float*)d_in[6];
  const float* q_ln_b   = (const float*)d_in[7];
  const float* k_ln_w   = (const float*)d_in[8];
  const float* k_ln_b   = (const float*)d_in[9];
  const float* wq       = (const float*)d_in[10];
  const float* wk       = (const float*)d_in[11];
  const float* wv       = (const float*)d_in[12];
  const float* wo       = (const float*)d_in[13];
  const float* mlp_ln_w = (const float*)d_in[14];
  const float* mlp_ln_b = (const float*)d_in[15];
  const float* w_fc     = (const float*)d_in[16];
  const float* w_cproj  = (const float*)d_in[17];
  const float* fin_w    = (const float*)d_in[18];
  const float* fin_b    = (const float*)d_in[19];

  char* ws = (char*)d_ws;
  u16*   normctx = (u16*)(ws + 0ull);            // [65536,1280] bf16
  u16*   Kbuf    = (u16*)(ws + 167772160ull);    // [32,2112,1536] bf16
  u16*   Vbuf    = (u16*)(ws + 375390208ull);    // [32,2112,1536] bf16
  float* lat     = (float*)(ws + 583008256ull);  // [2048,1280] f32
  u16*   latn    = (u16*)(ws + 593494016ull);    // [2048,1280] bf16
  u16*   mlpn    = (u16*)(ws + 598736896ull);    // [2048,1280] bf16
  u16*   qb      = (u16*)(ws + 603979776ull);    // [2048,1536] bf16
  u16*   res     = (u16*)(ws + 610271232ull);    // [2048,1536] bf16
  u16*   hb      = (u16*)(ws + 616562688ull);    // [2048,5120] bf16
  u16*   wT      = (u16*)(ws + 637534208ull);    // transposed weights
  float* biaskv  = (float*)(ws + 687341568ull);  // [3072]

  u16* wqT   = wT;                   // [1536,1280]
  u16* wkvT  = wT + 1966080;         // [3072,1280] (k then v, unfolded)
  u16* wkvfT = wT + 5898240;         // [3072,1280] (k then v, ctx_ln_w folded)
  u16* woT   = wT + 9830400;         // [1280,1536]
  u16* wfcT  = wT + 11796480;        // [5120,1280]
  u16* wcpT  = wT + 18350080;        // [1280,5120]

  const float qscale = 1.0f / sqrtf(96.0f);

  ln_rows<u16><<<65536, 320, 0, stream>>>(context, normctx, nullptr, nullptr);
  lat_init<<<2048, 320, 0, stream>>>(latents, lat);

  for (int i = 0; i < 3; ++i) {
    transcast<<<dim3(48, 40), 256, 0, stream>>>(wq + (size_t)i * 1966080, wqT, nullptr, 1280, 1536);
    transcast<<<dim3(48, 40), 256, 0, stream>>>(wk + (size_t)i * 1966080, wkvT, nullptr, 1280, 1536);
    transcast<<<dim3(48, 40), 256, 0, stream>>>(wv + (size_t)i * 1966080, wkvT + 1966080, nullptr, 1280, 1536);
    transcast<<<dim3(48, 40), 256, 0, stream>>>(wk + (size_t)i * 1966080, wkvfT, ctx_ln_w + i * 1280, 1280, 1536);
    transcast<<<dim3(48, 40), 256, 0, stream>>>(wv + (size_t)i * 1966080, wkvfT + 1966080, ctx_ln_w + i * 1280, 1280, 1536);
    transcast<<<dim3(40, 48), 256, 0, stream>>>(wo + (size_t)i * 1966080, woT, nullptr, 1536, 1280);
    transcast<<<dim3(160, 40), 256, 0, stream>>>(w_fc + (size_t)i * 6553600, wfcT, nullptr, 1280, 5120);
    transcast<<<dim3(40, 160), 256, 0, stream>>>(w_cproj + (size_t)i * 6553600, wcpT, nullptr, 5120, 1280);
    bias_dot<<<3072, 64, 0, stream>>>(wkvT, ctx_ln_b + i * 1280, biaskv, 1280);

    ln_rows<u16><<<2048, 320, 0, stream>>>(lat, latn, lat_ln_w + i * 1280, lat_ln_b + i * 1280);

    // ctx K/V fused: NEW 256x256 8-phase kernel. grid = 256*12 = 3072 (%8==0).
    gemm_kv256<<<3072, 512, 0, stream>>>(normctx, wkvfT, Kbuf, Vbuf, biaskv,
        1280, 1536, 11, 2112, 0, 12);
    // latent K/V rows: small, keep 128^2 kernel
    gemm_bf16<<<dim3(24, 16), 256, 0, stream>>>(latn, wkvT, Kbuf, Vbuf, nullptr, nullptr,
        2048, 3072, 1536, 1280, 6, 2112, 2048, 1 | 4);
    // Q
    gemm_bf16<<<dim3(12, 16), 256, 0, stream>>>(latn, wqT, qb, nullptr, nullptr, nullptr,
        2048, 1536, 1536, 1280, 11, 2048, 0, 1);

    seg_ln<<<8192, 256, 0, stream>>>(qb, q_ln_w + i * 96, q_ln_b + i * 96, qscale, 32768);
    seg_ln<<<270336, 256, 0, stream>>>(Kbuf, k_ln_w + i * 96, k_ln_b + i * 96, 1.0f, 1081344);

    attn_mfma<<<dim3(16, 32), 256, 0, stream>>>(qb, Kbuf, Vbuf, res);

    gemm_bf16<<<dim3(10, 16), 256, 0, stream>>>(res, woT, lat, nullptr, nullptr, lat,
        2048, 1280, 1280, 1536, 11, 2048, 0, 0);

    ln_rows<u16><<<2048, 320, 0, stream>>>(lat, mlpn, mlp_ln_w + i * 1280, mlp_ln_b + i * 1280);
    gemm_bf16<<<dim3(40, 16), 256, 0, stream>>>(mlpn, wfcT, hb, nullptr, nullptr, nullptr,
        2048, 5120, 5120, 1280, 11, 2048, 0, 1 | 2);
    gemm_bf16<<<dim3(10, 16), 256, 0, stream>>>(hb, wcpT, lat, nullptr, nullptr, lat,
        2048, 1280, 1280, 5120, 11, 2048, 0, 0);
  }

  ln_rows<float><<<2048, 320, 0, stream>>>(lat, (float*)d_out, fin_w, fin_b);
}

// Round 2
// 3644.785 us; speedup vs baseline: 1.7564x; 1.2254x over previous
//
#include <hip/hip_runtime.h>
#include <math.h>

typedef unsigned short u16;
typedef unsigned int u32;

typedef short bf16x8 __attribute__((ext_vector_type(8)));
typedef unsigned short u16x8 __attribute__((ext_vector_type(8)));
typedef float f32x4 __attribute__((ext_vector_type(4)));
typedef __attribute__((address_space(1))) const void gconst_t;
typedef __attribute__((address_space(3))) void lds_t;

__device__ __forceinline__ float bf2f(u16 u) {
  union { u32 i; float f; } v; v.i = ((u32)u) << 16; return v.f;
}
__device__ __forceinline__ u16 f2bf(float f) {
  union { float f; u32 i; } v; v.f = f;
  u32 r = v.i + 0x7fffu + ((v.i >> 16) & 1u);   // RNE
  return (u16)(r >> 16);
}

// ---------------------------------------------------------------------------
// Row LayerNorm over D=1280, block=320 threads (5 waves), one row per block.
// ---------------------------------------------------------------------------
__device__ __forceinline__ void store4(float* p, float4 y) { *(float4*)p = y; }
__device__ __forceinline__ void store4(u16* p, float4 y) {
  ushort4 u; u.x = f2bf(y.x); u.y = f2bf(y.y); u.z = f2bf(y.z); u.w = f2bf(y.w);
  *(ushort4*)p = u;
}

template <typename OutT>
__global__ __launch_bounds__(320) void ln_rows(const float* __restrict__ in,
    OutT* __restrict__ out, const float* __restrict__ w, const float* __restrict__ b)
{
  __shared__ float ps[5], pss[5];
  const int row = blockIdx.x, t = threadIdx.x;
  const float4 x = ((const float4*)(in + (size_t)row * 1280))[t];
  float s = x.x + x.y + x.z + x.w;
  float ss = x.x * x.x + x.y * x.y + x.z * x.z + x.w * x.w;
#pragma unroll
  for (int o = 32; o > 0; o >>= 1) { s += __shfl_xor(s, o); ss += __shfl_xor(ss, o); }
  if ((t & 63) == 0) { ps[t >> 6] = s; pss[t >> 6] = ss; }
  __syncthreads();
  s = ps[0] + ps[1] + ps[2] + ps[3] + ps[4];
  ss = pss[0] + pss[1] + pss[2] + pss[3] + pss[4];
  const float mean = s * (1.f / 1280.f);
  const float rstd = rsqrtf(ss * (1.f / 1280.f) - mean * mean + 1e-5f);
  float4 y;
  y.x = (x.x - mean) * rstd; y.y = (x.y - mean) * rstd;
  y.z = (x.z - mean) * rstd; y.w = (x.w - mean) * rstd;
  if (w) {
    const float4 wv4 = ((const float4*)w)[t];
    const float4 bv4 = ((const float4*)b)[t];
    y.x = y.x * wv4.x + bv4.x; y.y = y.y * wv4.y + bv4.y;
    y.z = y.z * wv4.z + bv4.z; y.w = y.w * wv4.w + bv4.w;
  }
  store4(out + (size_t)row * 1280 + t * 4, y);
}

// lat[r][:] = latents[r & 63][:]
__global__ __launch_bounds__(320) void lat_init(const float* __restrict__ latents,
                                                float* __restrict__ lat)
{
  const int r = blockIdx.x, t = threadIdx.x;
  ((float4*)(lat + (size_t)r * 1280))[t] =
      ((const float4*)(latents + (size_t)(r & 63) * 1280))[t];
}

// dst[n][k] = src[k][n] * (fold ? fold[k] : 1), cast to bf16. 32x32 LDS tiles.
__global__ __launch_bounds__(256) void transcast(const float* __restrict__ src,
    u16* __restrict__ dst, const float* __restrict__ fold, int K, int N)
{
  __shared__ float tile[32][33];
  const int n0 = blockIdx.x * 32, k0 = blockIdx.y * 32;
  const int tx = threadIdx.x & 31, ty = threadIdx.x >> 5;
#pragma unroll
  for (int r = ty; r < 32; r += 8) {
    float v = src[(size_t)(k0 + r) * N + n0 + tx];
    if (fold) v *= fold[k0 + r];
    tile[r][tx] = v;
  }
  __syncthreads();
#pragma unroll
  for (int r = ty; r < 32; r += 8)
    dst[(size_t)(n0 + r) * K + k0 + tx] = f2bf(tile[tx][r]);
}

// out[h] = sum_d bvec[d] * wT[h][d]   (wT bf16 [N][K])
__global__ __launch_bounds__(64) void bias_dot(const u16* __restrict__ wT,
    const float* __restrict__ bvec, float* __restrict__ outp, int K)
{
  const int h = blockIdx.x, lane = threadIdx.x;
  const u16* row = wT + (size_t)h * K;
  float s = 0.f;
  for (int i = lane; i < K; i += 64) s += bvec[i] * bf2f(row[i]);
#pragma unroll
  for (int o = 32; o > 0; o >>= 1) s += __shfl_xor(s, o);
  if (lane == 0) outp[h] = s;
}

// ---------------------------------------------------------------------------
// In-place LayerNorm over contiguous 96-element segments (q head-dim LN).
// ---------------------------------------------------------------------------
__global__ __launch_bounds__(256) void seg_ln(u16* __restrict__ buf,
    const float* __restrict__ w, const float* __restrict__ b, float scale, int nseg)
{
  const int seg = blockIdx.x * 4 + (threadIdx.x >> 6);
  if (seg >= nseg) return;
  const int lane = threadIdx.x & 63;
  u16* p = buf + (size_t)seg * 96;
  const float a = bf2f(p[lane]);
  const float c = (lane < 32) ? bf2f(p[64 + lane]) : 0.f;
  float s = a + c, ss = a * a + c * c;
#pragma unroll
  for (int o = 32; o > 0; o >>= 1) { s += __shfl_xor(s, o); ss += __shfl_xor(ss, o); }
  const float mean = s * (1.f / 96.f);
  const float rstd = rsqrtf(ss * (1.f / 96.f) - mean * mean + 1e-5f);
  p[lane] = f2bf(((a - mean) * rstd * w[lane] + b[lane]) * scale);
  if (lane < 32)
    p[64 + lane] = f2bf(((c - mean) * rstd * w[64 + lane] + b[64 + lane]) * scale);
}

// ---------------------------------------------------------------------------
// bf16 MFMA GEMM, m97 pattern. Block tile = 128 x (32*NF), 4 waves each
// 64 x (16*NF). NF=4: original 128x128. NF=2: 128x64 (2x grid for small N).
// flags: 1 = bf16 out, 2 = relu, 4 = column split at ldc (C0 then C1).
// out_row = (in_row >> sh)*bstride + off + (in_row & ((1<<sh)-1))
// ---------------------------------------------------------------------------
#define GTM 128
#define GBK 64

template <int NF>
__global__ __launch_bounds__(256) void gemm_bf16(
    const u16* __restrict__ A, const u16* __restrict__ BT,
    void* C0, void* C1, const float* __restrict__ bias, const float* resid,
    int M, int N, int ldc, int K, int sh, int bstride, int off, int flags)
{
  constexpr int TN = 32 * NF;
  __shared__ __align__(16) u16 As[GTM * GBK];
  __shared__ __align__(16) u16 Bs[TN * GBK];
  const int tid = threadIdx.x;
  const int lane = tid & 63;
  const int wv = tid >> 6;
  const int m0 = blockIdx.y * GTM;
  const int n0 = blockIdx.x * TN;
  const int wm = (wv >> 1) * 64;
  const int wn = (wv & 1) * (16 * NF);
  const int srow = lane >> 3;
  const int scol = (lane & 7) * 8;

  f32x4 acc[4][NF] = {};

  const u16* Ab = A + (size_t)m0 * K;
  const u16* Bb = BT + (size_t)n0 * K;

  for (int kt = 0; kt < K; kt += GBK) {
#pragma unroll
    for (int it = 0; it < 4; ++it) {
      const int r = wv * 32 + it * 8;
      const u16* ga = Ab + (size_t)(r + srow) * K + kt + scol;
      __builtin_amdgcn_global_load_lds((gconst_t*)ga, (lds_t*)(As + r * GBK), 16, 0, 0);
    }
#pragma unroll
    for (int it = 0; it < NF; ++it) {
      const int r = wv * (8 * NF) + it * 8;
      const u16* gb = Bb + (size_t)(r + srow) * K + kt + scol;
      __builtin_amdgcn_global_load_lds((gconst_t*)gb, (lds_t*)(Bs + r * GBK), 16, 0, 0);
    }
    __syncthreads();
#pragma unroll
    for (int ks = 0; ks < GBK; ks += 32) {
      bf16x8 af[4], bfr[NF];
      const int koff = ks + ((lane >> 4) << 3);
      const int rsel = lane & 15;
#pragma unroll
      for (int f = 0; f < 4; ++f)
        af[f] = *(const bf16x8*)(As + (wm + f * 16 + rsel) * GBK + koff);
#pragma unroll
      for (int f = 0; f < NF; ++f)
        bfr[f] = *(const bf16x8*)(Bs + (wn + f * 16 + rsel) * GBK + koff);
#pragma unroll
      for (int fm = 0; fm < 4; ++fm)
#pragma unroll
        for (int fn = 0; fn < NF; ++fn)
          acc[fm][fn] = __builtin_amdgcn_mfma_f32_16x16x32_bf16(
              af[fm], bfr[fn], acc[fm][fn], 0, 0, 0);
    }
    __syncthreads();
  }

  const int colb = n0 + wn + (lane & 15);
  const int rowb = m0 + wm + ((lane >> 4) << 2);
  const int msk = (1 << sh) - 1;
  const bool obf = flags & 1;
  const bool rel = flags & 2;
  const bool spl = flags & 4;
#pragma unroll
  for (int fm = 0; fm < 4; ++fm) {
#pragma unroll
    for (int r = 0; r < 4; ++r) {
      const int ir = rowb + fm * 16 + r;
      const size_t orow = (size_t)((ir >> sh) * bstride + off + (ir & msk));
#pragma unroll
      for (int fn = 0; fn < NF; ++fn) {
        const int col = colb + fn * 16;
        float v = acc[fm][fn][r];
        if (bias) v += bias[col];
        if (rel) v = fmaxf(v, 0.f);
        void* cp = C0;
        int cl = col;
        if (spl && col >= ldc) { cp = C1; cl = col - ldc; }
        const size_t idx = orow * (size_t)ldc + cl;
        if (resid) v += resid[idx];
        if (obf) ((u16*)cp)[idx] = f2bf(v);
        else ((float*)cp)[idx] = v;
      }
    }
  }
}

// ---------------------------------------------------------------------------
// 256x256-tile, BK=64, 8-wave, 8-phase bf16 GEMM (m201 schedule) for the ctx
// K/V projection. Counted-vmcnt gates folded into odd-phase tails (8 barriers
// per K-tile instead of 10).
// ---------------------------------------------------------------------------
__global__ __launch_bounds__(512, 2) void gemm_kv256(
    const u16* __restrict__ A, const u16* __restrict__ BT,
    u16* __restrict__ C0, u16* __restrict__ C1, const float* __restrict__ bias,
    int K, int ldc, int sh, int bstride, int off, int nbx)
{
  __shared__ __align__(16) u16 As[2][2][8192];   // [buf][kk][256*32]
  __shared__ __align__(16) u16 Bs[2][2][8192];   // 128 KiB total

  const int cpx = gridDim.x >> 3;
  int bid = blockIdx.x;
  bid = (bid & 7) * cpx + (bid >> 3);
  const int by = bid / nbx, bx = bid - by * nbx;

  const int tid = threadIdx.x, lane = tid & 63, wv = tid >> 6;
  const int quad = lane >> 4, rsel = lane & 15;
  const int wm = (wv >> 2) * 128, wn = (wv & 3) * 64;

  const u16* Ab = A + (size_t)(by * 256) * K;
  const u16* Bb = BT + (size_t)(bx * 256) * K;

  const int srow = wv * 16 + (lane >> 2);
  const int sgo  = (((lane & 3) ^ ((lane >> 3) & 3)) << 3);   // src granule swizzle
  const int gsw  = ((quad ^ ((rsel >> 1) & 3)) << 3);         // read granule swizzle

  const int KT = K >> 6;
  f32x4 acc[8][4] = {};

  auto stage = [&](int mat, int kk, int kt, int bsel) {
    const u16* g = mat ? Bb : Ab;
    u16* l = mat ? &Bs[bsel][kk][0] : &As[bsel][kk][0];
    const u16* s0 = g + (size_t)srow * K + kt * 64 + kk * 32 + sgo;
    __builtin_amdgcn_global_load_lds((gconst_t*)s0, (lds_t*)(l + tid * 8), 16, 0, 0);
    const u16* s1 = g + (size_t)(srow + 128) * K + kt * 64 + kk * 32 + sgo;
    __builtin_amdgcn_global_load_lds((gconst_t*)s1, (lds_t*)(l + 4096 + tid * 8), 16, 0, 0);
  };

  // prologue: tiles 0 and 1 fully staged; drain to tile-0-complete.
  stage(0, 0, 0, 0); stage(1, 0, 0, 0); stage(0, 1, 0, 0); stage(1, 1, 0, 0);
  stage(0, 0, 1, 1); stage(1, 0, 1, 1); stage(0, 1, 1, 1); stage(1, 1, 1, 1);
  asm volatile("s_waitcnt vmcnt(8)" ::: "memory");
  __builtin_amdgcn_s_barrier();
  asm volatile("" ::: "memory");

  for (int t = 0; t < KT; ++t) {
    const int c = t & 1;
    const u16* An = &As[c][0][0];
    const u16* Bn = &Bs[c][0][0];
    bf16x8 bb[4];
#pragma unroll
    for (int p = 0; p < 4; ++p) {
      const int kk = p >> 1, rh = p & 1;
      bf16x8 af[4];
      const u16* Ap = An + kk * 8192 + (wm + rh * 64 + rsel) * 32 + gsw;
#pragma unroll
      for (int f = 0; f < 4; ++f) af[f] = *(const bf16x8*)(Ap + f * 512);
      if (rh == 0) {
        const u16* Bp = Bn + kk * 8192 + (wn + rsel) * 32 + gsw;
#pragma unroll
        for (int g = 0; g < 4; ++g) bb[g] = *(const bf16x8*)(Bp + g * 512);
      }
      // stage one half-tile of k-tile t+1 (A-k0, B-k0, A-k1, B-k1 order)
      if (t >= 1 && t + 1 < KT) stage(p & 1, p >> 1, t + 1, (t + 1) & 1);
      __builtin_amdgcn_s_barrier();
      asm volatile("s_waitcnt lgkmcnt(0)" ::: "memory");
      __builtin_amdgcn_sched_barrier(0);           // rule #18
      __builtin_amdgcn_s_setprio(1);               // T5
#pragma unroll
      for (int f = 0; f < 4; ++f)
#pragma unroll
        for (int g = 0; g < 4; ++g)
          acc[rh * 4 + f][g] = __builtin_amdgcn_mfma_f32_16x16x32_bf16(
              af[f], bb[g], acc[rh * 4 + f][g], 0, 0, 0);
      __builtin_amdgcn_s_setprio(0);
      __builtin_amdgcn_sched_barrier(0);
      // counted-vmcnt gate folded into odd-phase tails: FIFO trace gives
      // exactly {4,...,4, 0(last tile ph1)}; never drains mid-loop.
      if (rh == 1) {
        if (t < KT - 1)      asm volatile("s_waitcnt vmcnt(4)" ::: "memory");
        else if (p == 1)     asm volatile("s_waitcnt vmcnt(0)" ::: "memory");
      }
      __builtin_amdgcn_s_barrier();
      asm volatile("" ::: "memory");
    }
  }

  const bool isv = (bx * 256) >= ldc;
  u16* Cb = isv ? C1 : C0;
  const int cb0 = bx * 256 - (isv ? ldc : 0);
  const int colb = cb0 + wn + rsel;
  const int bcol = bx * 256 + wn + rsel;
  const int rowb = by * 256 + wm + quad * 4;
  const int msk = (1 << sh) - 1;
#pragma unroll
  for (int fm = 0; fm < 8; ++fm) {
#pragma unroll
    for (int r = 0; r < 4; ++r) {
      const int ir = rowb + fm * 16 + r;
      const size_t orow = (size_t)((ir >> sh) * bstride + off + (ir & msk));
      u16* cp = Cb + orow * (size_t)ldc;
#pragma unroll
      for (int fn = 0; fn < 4; ++fn) {
        const float v = acc[fm][fn][r] + bias[bcol + fn * 16];
        cp[colb + fn * 16] = f2bf(v);
      }
    }
  }
}

// ---------------------------------------------------------------------------
// MFMA flash attention with FOLDED per-head K LayerNorm. One block per
// (h=blockIdx.x, b=blockIdx.y), 4 waves. K is staged raw (pre-LN) from Kbuf;
// LN over the 96-wide head slice is applied in-LDS on the staged tile
// (identical f32 math + f2bf rounding as the old seg_ln kernel), which
// deletes the 415 MB/layer seg_ln pass entirely.
// ---------------------------------------------------------------------------
__global__ __launch_bounds__(256) void attn_mfma(
    const u16* __restrict__ Q, const u16* __restrict__ Kb,
    const u16* __restrict__ Vb, u16* __restrict__ Res,
    const float* __restrict__ kwp, const float* __restrict__ kbp)
{
  __shared__ __align__(16) u16 Ks[64 * 104];
  __shared__ __align__(16) u16 Vt[96 * 72];
  __shared__ __align__(16) u16 Ps[4][16 * 72];
  const int h = blockIdx.x, b = blockIdx.y;
  const int t = threadIdx.x, lane = t & 63, wv = t >> 6;
  const int quad = lane >> 4, rsel = lane & 15;

  // per-lane LN coefficients: this lane normalizes cols [quad*24, +24)
  float kw[24], kb[24];
#pragma unroll
  for (int j = 0; j < 6; ++j) {
    const float4 a = *(const float4*)(kwp + quad * 24 + j * 4);
    const float4 c = *(const float4*)(kbp + quad * 24 + j * 4);
    kw[j * 4 + 0] = a.x; kw[j * 4 + 1] = a.y; kw[j * 4 + 2] = a.z; kw[j * 4 + 3] = a.w;
    kb[j * 4 + 0] = c.x; kb[j * 4 + 1] = c.y; kb[j * 4 + 2] = c.z; kb[j * 4 + 3] = c.w;
  }

  bf16x8 aq[3];
  const int qrow0 = b * 64 + wv * 16;
  {
    const u16* qp = Q + (size_t)(qrow0 + rsel) * 1536 + h * 96 + quad * 8;
    aq[0] = *(const bf16x8*)(qp);
    aq[1] = *(const bf16x8*)(qp + 32);
    aq[2] = *(const bf16x8*)(qp + 64);
  }

  f32x4 accO[6] = {};
  float mrow[4] = {-1e30f, -1e30f, -1e30f, -1e30f};
  float lrow[4] = {0.f, 0.f, 0.f, 0.f};

  const size_t kvbase = (size_t)b * 2112 * 1536 + (size_t)h * 96;
  u16* ps = Ps[wv];

  for (int tile = 0; tile < 33; ++tile) {
    __syncthreads();
    // ---- stage K chunk [64][96] -> Ks[64][104] ----
#pragma unroll
    for (int it = 0; it < 3; ++it) {
      const int e0 = (((wv * 3 + it) << 6) + lane) << 3;
      const int j = e0 / 96, d = e0 - j * 96;
      const u16x8 k8 = *(const u16x8*)(Kb + kvbase + (size_t)(tile * 64 + j) * 1536 + d);
      *(u16x8*)(Ks + j * 104 + d) = k8;
    }
    // ---- stage V chunk transposed -> Vt[96][72] ----
#pragma unroll
    for (int it = 0; it < 3; ++it) {
      const int g = ((wv * 3 + it) << 6) + lane;
      const int kvp = g & 31, dr = g >> 5;
      const size_t ga = kvbase + (size_t)(tile * 64 + kvp * 2) * 1536 + dr * 4;
      const ushort4 va = *(const ushort4*)(Vb + ga);
      const ushort4 vb4 = *(const ushort4*)(Vb + ga + 1536);
      u32* vt = (u32*)Vt;
      vt[(dr * 4 + 0) * 36 + kvp] = (u32)va.x | ((u32)vb4.x << 16);
      vt[(dr * 4 + 1) * 36 + kvp] = (u32)va.y | ((u32)vb4.y << 16);
      vt[(dr * 4 + 2) * 36 + kvp] = (u32)va.z | ((u32)vb4.z << 16);
      vt[(dr * 4 + 3) * 36 + kvp] = (u32)va.w | ((u32)vb4.w << 16);
    }
    __syncthreads();

    // ---- folded K head-LN on the staged tile: row = wv*16+rsel, cols by quad
    {
      const int r = (wv << 4) + rsel;
      u16* kr = Ks + r * 104 + quad * 24;
      float x[24];
#pragma unroll
      for (int j = 0; j < 6; ++j) {
        const ushort4 raw = *(const ushort4*)(kr + j * 4);
        x[j * 4 + 0] = bf2f(raw.x); x[j * 4 + 1] = bf2f(raw.y);
        x[j * 4 + 2] = bf2f(raw.z); x[j * 4 + 3] = bf2f(raw.w);
      }
      float s = 0.f, ss = 0.f;
#pragma unroll
      for (int j = 0; j < 24; ++j) { s += x[j]; ss += x[j] * x[j]; }
      s += __shfl_xor(s, 16); ss += __shfl_xor(ss, 16);
      s += __shfl_xor(s, 32); ss += __shfl_xor(ss, 32);
      const float mean = s * (1.f / 96.f);
      const float rstd = rsqrtf(ss * (1.f / 96.f) - mean * mean + 1e-5f);
#pragma unroll
      for (int j = 0; j < 6; ++j) {
        ushort4 o;
        o.x = f2bf((x[j * 4 + 0] - mean) * rstd * kw[j * 4 + 0] + kb[j * 4 + 0]);
        o.y = f2bf((x[j * 4 + 1] - mean) * rstd * kw[j * 4 + 1] + kb[j * 4 + 1]);
        o.z = f2bf((x[j * 4 + 2] - mean) * rstd * kw[j * 4 + 2] + kb[j * 4 + 2]);
        o.w = f2bf((x[j * 4 + 3] - mean) * rstd * kw[j * 4 + 3] + kb[j * 4 + 3]);
        *(ushort4*)(kr + j * 4) = o;
      }
    }
    __syncthreads();

    // ---- S = Q * K^T ----
    f32x4 accS[4] = {};
#pragma unroll
    for (int nt = 0; nt < 4; ++nt) {
#pragma unroll
      for (int kt = 0; kt < 3; ++kt) {
        const bf16x8 bk = *(const bf16x8*)(Ks + (nt * 16 + rsel) * 104 + kt * 32 + quad * 8);
        accS[nt] = __builtin_amdgcn_mfma_f32_16x16x32_bf16(aq[kt], bk, accS[nt], 0, 0, 0);
      }
    }

    // ---- online softmax ----
    float alpha[4], rs[4];
#pragma unroll
    for (int r = 0; r < 4; ++r) {
      float mt = fmaxf(fmaxf(accS[0][r], accS[1][r]), fmaxf(accS[2][r], accS[3][r]));
      mt = fmaxf(mt, __shfl_xor(mt, 1));
      mt = fmaxf(mt, __shfl_xor(mt, 2));
      mt = fmaxf(mt, __shfl_xor(mt, 4));
      mt = fmaxf(mt, __shfl_xor(mt, 8));
      const float nm = fmaxf(mrow[r], mt);
      alpha[r] = __expf(mrow[r] - nm);
      mrow[r] = nm;
      rs[r] = 0.f;
    }
#pragma unroll
    for (int nt = 0; nt < 4; ++nt)
#pragma unroll
      for (int r = 0; r < 4; ++r) {
        const float p = __expf(accS[nt][r] - mrow[r]);
        accS[nt][r] = p;
        rs[r] += p;
      }
#pragma unroll
    for (int r = 0; r < 4; ++r) {
      rs[r] += __shfl_xor(rs[r], 1);
      rs[r] += __shfl_xor(rs[r], 2);
      rs[r] += __shfl_xor(rs[r], 4);
      rs[r] += __shfl_xor(rs[r], 8);
      lrow[r] = lrow[r] * alpha[r] + rs[r];
    }
#pragma unroll
    for (int nd = 0; nd < 6; ++nd)
#pragma unroll
      for (int r = 0; r < 4; ++r) accO[nd][r] *= alpha[r];

#pragma unroll
    for (int nt = 0; nt < 4; ++nt)
#pragma unroll
      for (int r = 0; r < 4; ++r)
        ps[(quad * 4 + r) * 72 + nt * 16 + rsel] = f2bf(accS[nt][r]);

#pragma unroll
    for (int kt = 0; kt < 2; ++kt) {
      const bf16x8 ap = *(const bf16x8*)(ps + rsel * 72 + kt * 32 + quad * 8);
#pragma unroll
      for (int nd = 0; nd < 6; ++nd) {
        const bf16x8 bv = *(const bf16x8*)(Vt + (nd * 16 + rsel) * 72 + kt * 32 + quad * 8);
        accO[nd] = __builtin_amdgcn_mfma_f32_16x16x32_bf16(ap, bv, accO[nd], 0, 0, 0);
      }
    }
  }

  float il[4];
#pragma unroll
  for (int r = 0; r < 4; ++r) il[r] = 1.f / lrow[r];
#pragma unroll
  for (int nd = 0; nd < 6; ++nd)
#pragma unroll
    for (int r = 0; r < 4; ++r)
      Res[(size_t)(qrow0 + quad * 4 + r) * 1536 + h * 96 + nd * 16 + rsel] =
          f2bf(accO[nd][r] * il[r]);
}

// ---------------------------------------------------------------------------
extern "C" void kernel_launch(void* const* d_in, const int* in_sizes, int n_in,
                              void* d_out, int out_size, void* d_ws, size_t ws_size,
                              hipStream_t stream) {
  const float* context  = (const float*)d_in[0];
  const float* latents  = (const float*)d_in[1];
  const float* ctx_ln_w = (const float*)d_in[2];
  const float* ctx_ln_b = (const float*)d_in[3];
  const float* lat_ln_w = (const float*)d_in[4];
  const float* lat_ln_b = (const float*)d_in[5];
  const float* q_ln_w   = (const float*)d_in[6];
  const float* q_ln_b   = (const float*)d_in[7];
  const float* k_ln_w   = (const float*)d_in[8];
  const float* k_ln_b   = (const float*)d_in[9];
  const float* wq       = (const float*)d_in[10];
  const float* wk       = (const float*)d_in[11];
  const float* wv       = (const float*)d_in[12];
  const float* wo       = (const float*)d_in[13];
  const float* mlp_ln_w = (const float*)d_in[14];
  const float* mlp_ln_b = (const float*)d_in[15];
  const float* w_fc     = (const float*)d_in[16];
  const float* w_cproj  = (const float*)d_in[17];
  const float* fin_w    = (const float*)d_in[18];
  const float* fin_b    = (const float*)d_in[19];

  char* ws = (char*)d_ws;
  u16*   normctx = (u16*)(ws + 0ull);            // [65536,1280] bf16
  u16*   Kbuf    = (u16*)(ws + 167772160ull);    // [32,2112,1536] bf16
  u16*   Vbuf    = (u16*)(ws + 375390208ull);    // [32,2112,1536] bf16
  float* lat     = (float*)(ws + 583008256ull);  // [2048,1280] f32
  u16*   latn    = (u16*)(ws + 593494016ull);    // [2048,1280] bf16
  u16*   mlpn    = (u16*)(ws + 598736896ull);    // [2048,1280] bf16
  u16*   qb      = (u16*)(ws + 603979776ull);    // [2048,1536] bf16
  u16*   res     = (u16*)(ws + 610271232ull);    // [2048,1536] bf16
  u16*   hb      = (u16*)(ws + 616562688ull);    // [2048,5120] bf16
  u16*   wT      = (u16*)(ws + 637534208ull);    // transposed weights
  float* biaskv  = (float*)(ws + 687341568ull);  // [3072]

  u16* wqT   = wT;                   // [1536,1280]
  u16* wkvT  = wT + 1966080;         // [3072,1280] (k then v, unfolded)
  u16* wkvfT = wT + 5898240;         // [3072,1280] (k then v, ctx_ln_w folded)
  u16* woT   = wT + 9830400;         // [1280,1536]
  u16* wfcT  = wT + 11796480;        // [5120,1280]
  u16* wcpT  = wT + 18350080;        // [1280,5120]

  const float qscale = 1.0f / sqrtf(96.0f);

  ln_rows<u16><<<65536, 320, 0, stream>>>(context, normctx, nullptr, nullptr);
  lat_init<<<2048, 320, 0, stream>>>(latents, lat);

  for (int i = 0; i < 3; ++i) {
    transcast<<<dim3(48, 40), 256, 0, stream>>>(wq + (size_t)i * 1966080, wqT, nullptr, 1280, 1536);
    transcast<<<dim3(48, 40), 256, 0, stream>>>(wk + (size_t)i * 1966080, wkvT, nullptr, 1280, 1536);
    transcast<<<dim3(48, 40), 256, 0, stream>>>(wv + (size_t)i * 1966080, wkvT + 1966080, nullptr, 1280, 1536);
    transcast<<<dim3(48, 40), 256, 0, stream>>>(wk + (size_t)i * 1966080, wkvfT, ctx_ln_w + i * 1280, 1280, 1536);
    transcast<<<dim3(48, 40), 256, 0, stream>>>(wv + (size_t)i * 1966080, wkvfT + 1966080, ctx_ln_w + i * 1280, 1280, 1536);
    transcast<<<dim3(40, 48), 256, 0, stream>>>(wo + (size_t)i * 1966080, woT, nullptr, 1536, 1280);
    transcast<<<dim3(160, 40), 256, 0, stream>>>(w_fc + (size_t)i * 6553600, wfcT, nullptr, 1280, 5120);
    transcast<<<dim3(40, 160), 256, 0, stream>>>(w_cproj + (size_t)i * 6553600, wcpT, nullptr, 5120, 1280);
    bias_dot<<<3072, 64, 0, stream>>>(wkvT, ctx_ln_b + i * 1280, biaskv, 1280);

    ln_rows<u16><<<2048, 320, 0, stream>>>(lat, latn, lat_ln_w + i * 1280, lat_ln_b + i * 1280);

    // ctx K/V fused: 256x256 8-phase kernel. grid = 256*12 = 3072 (%8==0).
    gemm_kv256<<<3072, 512, 0, stream>>>(normctx, wkvfT, Kbuf, Vbuf, biaskv,
        1280, 1536, 11, 2112, 0, 12);
    // latent K/V rows
    gemm_bf16<4><<<dim3(24, 16), 256, 0, stream>>>(latn, wkvT, Kbuf, Vbuf, nullptr, nullptr,
        2048, 3072, 1536, 1280, 6, 2112, 2048, 1 | 4);
    // Q (128x64 tiles -> 384 blocks)
    gemm_bf16<2><<<dim3(24, 16), 256, 0, stream>>>(latn, wqT, qb, nullptr, nullptr, nullptr,
        2048, 1536, 1536, 1280, 11, 2048, 0, 1);

    // per-head LN on q (qk_scale folded); K-LN is folded into attn staging.
    seg_ln<<<8192, 256, 0, stream>>>(qb, q_ln_w + i * 96, q_ln_b + i * 96, qscale, 32768);

    attn_mfma<<<dim3(16, 32), 256, 0, stream>>>(qb, Kbuf, Vbuf, res,
        k_ln_w + i * 96, k_ln_b + i * 96);

    // lat = res @ wo + lat  (128x64 tiles -> 320 blocks)
    gemm_bf16<2><<<dim3(20, 16), 256, 0, stream>>>(res, woT, lat, nullptr, nullptr, lat,
        2048, 1280, 1280, 1536, 11, 2048, 0, 0);

    // MLP
    ln_rows<u16><<<2048, 320, 0, stream>>>(lat, mlpn, mlp_ln_w + i * 1280, mlp_ln_b + i * 1280);
    gemm_bf16<4><<<dim3(40, 16), 256, 0, stream>>>(mlpn, wfcT, hb, nullptr, nullptr, nullptr,
        2048, 5120, 5120, 1280, 11, 2048, 0, 1 | 2);
    gemm_bf16<2><<<dim3(20, 16), 256, 0, stream>>>(hb, wcpT, lat, nullptr, nullptr, lat,
        2048, 1280, 1280, 5120, 11, 2048, 0, 0);
  }

  ln_rows<float><<<2048, 320, 0, stream>>>(lat, (float*)d_out, fin_w, fin_b);
}

// Round 3
// 3598.648 us; speedup vs baseline: 1.7790x; 1.0128x over previous
//
#include <hip/hip_runtime.h>
#include <math.h>

typedef unsigned short u16;
typedef unsigned int u32;

typedef short bf16x8 __attribute__((ext_vector_type(8)));
typedef unsigned short u16x8 __attribute__((ext_vector_type(8)));
typedef float f32x4 __attribute__((ext_vector_type(4)));
typedef __attribute__((address_space(1))) const void gconst_t;
typedef __attribute__((address_space(3))) void lds_t;

__device__ __forceinline__ float bf2f(u16 u) {
  union { u32 i; float f; } v; v.i = ((u32)u) << 16; return v.f;
}
__device__ __forceinline__ u16 f2bf(float f) {
  union { float f; u32 i; } v; v.f = f;
  u32 r = v.i + 0x7fffu + ((v.i >> 16) & 1u);   // RNE
  return (u16)(r >> 16);
}

// ---------------------------------------------------------------------------
// Row LayerNorm over D=1280, block=320 threads (5 waves), one row per block.
// ---------------------------------------------------------------------------
__device__ __forceinline__ void store4(float* p, float4 y) { *(float4*)p = y; }
__device__ __forceinline__ void store4(u16* p, float4 y) {
  ushort4 u; u.x = f2bf(y.x); u.y = f2bf(y.y); u.z = f2bf(y.z); u.w = f2bf(y.w);
  *(ushort4*)p = u;
}

template <typename OutT>
__global__ __launch_bounds__(320) void ln_rows(const float* __restrict__ in,
    OutT* __restrict__ out, const float* __restrict__ w, const float* __restrict__ b)
{
  __shared__ float ps[5], pss[5];
  const int row = blockIdx.x, t = threadIdx.x;
  const float4 x = ((const float4*)(in + (size_t)row * 1280))[t];
  float s = x.x + x.y + x.z + x.w;
  float ss = x.x * x.x + x.y * x.y + x.z * x.z + x.w * x.w;
#pragma unroll
  for (int o = 32; o > 0; o >>= 1) { s += __shfl_xor(s, o); ss += __shfl_xor(ss, o); }
  if ((t & 63) == 0) { ps[t >> 6] = s; pss[t >> 6] = ss; }
  __syncthreads();
  s = ps[0] + ps[1] + ps[2] + ps[3] + ps[4];
  ss = pss[0] + pss[1] + pss[2] + pss[3] + pss[4];
  const float mean = s * (1.f / 1280.f);
  const float rstd = rsqrtf(ss * (1.f / 1280.f) - mean * mean + 1e-5f);
  float4 y;
  y.x = (x.x - mean) * rstd; y.y = (x.y - mean) * rstd;
  y.z = (x.z - mean) * rstd; y.w = (x.w - mean) * rstd;
  if (w) {
    const float4 wv4 = ((const float4*)w)[t];
    const float4 bv4 = ((const float4*)b)[t];
    y.x = y.x * wv4.x + bv4.x; y.y = y.y * wv4.y + bv4.y;
    y.z = y.z * wv4.z + bv4.z; y.w = y.w * wv4.w + bv4.w;
  }
  store4(out + (size_t)row * 1280 + t * 4, y);
}

// lat[r][:] = latents[r & 63][:]
__global__ __launch_bounds__(320) void lat_init(const float* __restrict__ latents,
                                                float* __restrict__ lat)
{
  const int r = blockIdx.x, t = threadIdx.x;
  ((float4*)(lat + (size_t)r * 1280))[t] =
      ((const float4*)(latents + (size_t)(r & 63) * 1280))[t];
}

// dst[n][k] = src[k][n] * (fold ? fold[k] : 1), cast to bf16. 32x32 LDS tiles.
__global__ __launch_bounds__(256) void transcast(const float* __restrict__ src,
    u16* __restrict__ dst, const float* __restrict__ fold, int K, int N)
{
  __shared__ float tile[32][33];
  const int n0 = blockIdx.x * 32, k0 = blockIdx.y * 32;
  const int tx = threadIdx.x & 31, ty = threadIdx.x >> 5;
#pragma unroll
  for (int r = ty; r < 32; r += 8) {
    float v = src[(size_t)(k0 + r) * N + n0 + tx];
    if (fold) v *= fold[k0 + r];
    tile[r][tx] = v;
  }
  __syncthreads();
#pragma unroll
  for (int r = ty; r < 32; r += 8)
    dst[(size_t)(n0 + r) * K + k0 + tx] = f2bf(tile[tx][r]);
}

// out[h] = sum_d bvec[d] * wT[h][d]   (wT bf16 [N][K])
__global__ __launch_bounds__(64) void bias_dot(const u16* __restrict__ wT,
    const float* __restrict__ bvec, float* __restrict__ outp, int K)
{
  const int h = blockIdx.x, lane = threadIdx.x;
  const u16* row = wT + (size_t)h * K;
  float s = 0.f;
  for (int i = lane; i < K; i += 64) s += bvec[i] * bf2f(row[i]);
#pragma unroll
  for (int o = 32; o > 0; o >>= 1) s += __shfl_xor(s, o);
  if (lane == 0) outp[h] = s;
}

// ---------------------------------------------------------------------------
// In-place LayerNorm over contiguous 96-element segments (q head-dim LN).
// ---------------------------------------------------------------------------
__global__ __launch_bounds__(256) void seg_ln(u16* __restrict__ buf,
    const float* __restrict__ w, const float* __restrict__ b, float scale, int nseg)
{
  const int seg = blockIdx.x * 4 + (threadIdx.x >> 6);
  if (seg >= nseg) return;
  const int lane = threadIdx.x & 63;
  u16* p = buf + (size_t)seg * 96;
  const float a = bf2f(p[lane]);
  const float c = (lane < 32) ? bf2f(p[64 + lane]) : 0.f;
  float s = a + c, ss = a * a + c * c;
#pragma unroll
  for (int o = 32; o > 0; o >>= 1) { s += __shfl_xor(s, o); ss += __shfl_xor(ss, o); }
  const float mean = s * (1.f / 96.f);
  const float rstd = rsqrtf(ss * (1.f / 96.f) - mean * mean + 1e-5f);
  p[lane] = f2bf(((a - mean) * rstd * w[lane] + b[lane]) * scale);
  if (lane < 32)
    p[64 + lane] = f2bf(((c - mean) * rstd * w[64 + lane] + b[64 + lane]) * scale);
}

// ---------------------------------------------------------------------------
// bf16 MFMA GEMM, m97 pattern. Block tile = 128 x (32*NF), 4 waves each
// 64 x (16*NF). NF=4: original 128x128. NF=2: 128x64 (2x grid for small N).
// flags: 1 = bf16 out, 2 = relu, 4 = column split at ldc (C0 then C1).
// out_row = (in_row >> sh)*bstride + off + (in_row & ((1<<sh)-1))
// ---------------------------------------------------------------------------
#define GTM 128
#define GBK 64

template <int NF>
__global__ __launch_bounds__(256) void gemm_bf16(
    const u16* __restrict__ A, const u16* __restrict__ BT,
    void* C0, void* C1, const float* __restrict__ bias, const float* resid,
    int M, int N, int ldc, int K, int sh, int bstride, int off, int flags)
{
  constexpr int TN = 32 * NF;
  __shared__ __align__(16) u16 As[GTM * GBK];
  __shared__ __align__(16) u16 Bs[TN * GBK];
  const int tid = threadIdx.x;
  const int lane = tid & 63;
  const int wv = tid >> 6;
  const int m0 = blockIdx.y * GTM;
  const int n0 = blockIdx.x * TN;
  const int wm = (wv >> 1) * 64;
  const int wn = (wv & 1) * (16 * NF);
  const int srow = lane >> 3;
  const int scol = (lane & 7) * 8;

  f32x4 acc[4][NF] = {};

  const u16* Ab = A + (size_t)m0 * K;
  const u16* Bb = BT + (size_t)n0 * K;

  for (int kt = 0; kt < K; kt += GBK) {
#pragma unroll
    for (int it = 0; it < 4; ++it) {
      const int r = wv * 32 + it * 8;
      const u16* ga = Ab + (size_t)(r + srow) * K + kt + scol;
      __builtin_amdgcn_global_load_lds((gconst_t*)ga, (lds_t*)(As + r * GBK), 16, 0, 0);
    }
#pragma unroll
    for (int it = 0; it < NF; ++it) {
      const int r = wv * (8 * NF) + it * 8;
      const u16* gb = Bb + (size_t)(r + srow) * K + kt + scol;
      __builtin_amdgcn_global_load_lds((gconst_t*)gb, (lds_t*)(Bs + r * GBK), 16, 0, 0);
    }
    __syncthreads();
#pragma unroll
    for (int ks = 0; ks < GBK; ks += 32) {
      bf16x8 af[4], bfr[NF];
      const int koff = ks + ((lane >> 4) << 3);
      const int rsel = lane & 15;
#pragma unroll
      for (int f = 0; f < 4; ++f)
        af[f] = *(const bf16x8*)(As + (wm + f * 16 + rsel) * GBK + koff);
#pragma unroll
      for (int f = 0; f < NF; ++f)
        bfr[f] = *(const bf16x8*)(Bs + (wn + f * 16 + rsel) * GBK + koff);
#pragma unroll
      for (int fm = 0; fm < 4; ++fm)
#pragma unroll
        for (int fn = 0; fn < NF; ++fn)
          acc[fm][fn] = __builtin_amdgcn_mfma_f32_16x16x32_bf16(
              af[fm], bfr[fn], acc[fm][fn], 0, 0, 0);
    }
    __syncthreads();
  }

  const int colb = n0 + wn + (lane & 15);
  const int rowb = m0 + wm + ((lane >> 4) << 2);
  const int msk = (1 << sh) - 1;
  const bool obf = flags & 1;
  const bool rel = flags & 2;
  const bool spl = flags & 4;
#pragma unroll
  for (int fm = 0; fm < 4; ++fm) {
#pragma unroll
    for (int r = 0; r < 4; ++r) {
      const int ir = rowb + fm * 16 + r;
      const size_t orow = (size_t)((ir >> sh) * bstride + off + (ir & msk));
#pragma unroll
      for (int fn = 0; fn < NF; ++fn) {
        const int col = colb + fn * 16;
        float v = acc[fm][fn][r];
        if (bias) v += bias[col];
        if (rel) v = fmaxf(v, 0.f);
        void* cp = C0;
        int cl = col;
        if (spl && col >= ldc) { cp = C1; cl = col - ldc; }
        const size_t idx = orow * (size_t)ldc + cl;
        if (resid) v += resid[idx];
        if (obf) ((u16*)cp)[idx] = f2bf(v);
        else ((float*)cp)[idx] = v;
      }
    }
  }
}

// ---------------------------------------------------------------------------
// 256x256-tile, BK=64, 8-wave, 8-phase bf16 GEMM (m201 schedule) for the ctx
// K/V projection.
// ---------------------------------------------------------------------------
__global__ __launch_bounds__(512, 2) void gemm_kv256(
    const u16* __restrict__ A, const u16* __restrict__ BT,
    u16* __restrict__ C0, u16* __restrict__ C1, const float* __restrict__ bias,
    int K, int ldc, int sh, int bstride, int off, int nbx)
{
  __shared__ __align__(16) u16 As[2][2][8192];   // [buf][kk][256*32]
  __shared__ __align__(16) u16 Bs[2][2][8192];   // 128 KiB total

  const int cpx = gridDim.x >> 3;
  int bid = blockIdx.x;
  bid = (bid & 7) * cpx + (bid >> 3);
  const int by = bid / nbx, bx = bid - by * nbx;

  const int tid = threadIdx.x, lane = tid & 63, wv = tid >> 6;
  const int quad = lane >> 4, rsel = lane & 15;
  const int wm = (wv >> 2) * 128, wn = (wv & 3) * 64;

  const u16* Ab = A + (size_t)(by * 256) * K;
  const u16* Bb = BT + (size_t)(bx * 256) * K;

  const int srow = wv * 16 + (lane >> 2);
  const int sgo  = (((lane & 3) ^ ((lane >> 3) & 3)) << 3);   // src granule swizzle
  const int gsw  = ((quad ^ ((rsel >> 1) & 3)) << 3);         // read granule swizzle

  const int KT = K >> 6;
  f32x4 acc[8][4] = {};

  auto stage = [&](int mat, int kk, int kt, int bsel) {
    const u16* g = mat ? Bb : Ab;
    u16* l = mat ? &Bs[bsel][kk][0] : &As[bsel][kk][0];
    const u16* s0 = g + (size_t)srow * K + kt * 64 + kk * 32 + sgo;
    __builtin_amdgcn_global_load_lds((gconst_t*)s0, (lds_t*)(l + tid * 8), 16, 0, 0);
    const u16* s1 = g + (size_t)(srow + 128) * K + kt * 64 + kk * 32 + sgo;
    __builtin_amdgcn_global_load_lds((gconst_t*)s1, (lds_t*)(l + 4096 + tid * 8), 16, 0, 0);
  };

  // prologue: tiles 0 and 1 fully staged; drain to tile-0-complete.
  stage(0, 0, 0, 0); stage(1, 0, 0, 0); stage(0, 1, 0, 0); stage(1, 1, 0, 0);
  stage(0, 0, 1, 1); stage(1, 0, 1, 1); stage(0, 1, 1, 1); stage(1, 1, 1, 1);
  asm volatile("s_waitcnt vmcnt(8)" ::: "memory");
  __builtin_amdgcn_s_barrier();
  asm volatile("" ::: "memory");

  for (int t = 0; t < KT; ++t) {
    const int c = t & 1;
    const u16* An = &As[c][0][0];
    const u16* Bn = &Bs[c][0][0];
    bf16x8 bb[4];
#pragma unroll
    for (int p = 0; p < 4; ++p) {
      const int kk = p >> 1, rh = p & 1;
      bf16x8 af[4];
      const u16* Ap = An + kk * 8192 + (wm + rh * 64 + rsel) * 32 + gsw;
#pragma unroll
      for (int f = 0; f < 4; ++f) af[f] = *(const bf16x8*)(Ap + f * 512);
      if (rh == 0) {
        const u16* Bp = Bn + kk * 8192 + (wn + rsel) * 32 + gsw;
#pragma unroll
        for (int g = 0; g < 4; ++g) bb[g] = *(const bf16x8*)(Bp + g * 512);
      }
      if (t >= 1 && t + 1 < KT) stage(p & 1, p >> 1, t + 1, (t + 1) & 1);
      __builtin_amdgcn_s_barrier();
      asm volatile("s_waitcnt lgkmcnt(0)" ::: "memory");
      __builtin_amdgcn_sched_barrier(0);           // rule #18
      __builtin_amdgcn_s_setprio(1);               // T5
#pragma unroll
      for (int f = 0; f < 4; ++f)
#pragma unroll
        for (int g = 0; g < 4; ++g)
          acc[rh * 4 + f][g] = __builtin_amdgcn_mfma_f32_16x16x32_bf16(
              af[f], bb[g], acc[rh * 4 + f][g], 0, 0, 0);
      __builtin_amdgcn_s_setprio(0);
      __builtin_amdgcn_sched_barrier(0);
      if (rh == 1) {
        if (t < KT - 1)      asm volatile("s_waitcnt vmcnt(4)" ::: "memory");
        else if (p == 1)     asm volatile("s_waitcnt vmcnt(0)" ::: "memory");
      }
      __builtin_amdgcn_s_barrier();
      asm volatile("" ::: "memory");
    }
  }

  const bool isv = (bx * 256) >= ldc;
  u16* Cb = isv ? C1 : C0;
  const int cb0 = bx * 256 - (isv ? ldc : 0);
  const int colb = cb0 + wn + rsel;
  const int bcol = bx * 256 + wn + rsel;
  const int rowb = by * 256 + wm + quad * 4;
  const int msk = (1 << sh) - 1;
#pragma unroll
  for (int fm = 0; fm < 8; ++fm) {
#pragma unroll
    for (int r = 0; r < 4; ++r) {
      const int ir = rowb + fm * 16 + r;
      const size_t orow = (size_t)((ir >> sh) * bstride + off + (ir & msk));
      u16* cp = Cb + orow * (size_t)ldc;
#pragma unroll
      for (int fn = 0; fn < 4; ++fn) {
        const float v = acc[fm][fn][r] + bias[bcol + fn * 16];
        cp[colb + fn * 16] = f2bf(v);
      }
    }
  }
}

// ---------------------------------------------------------------------------
// MFMA flash attention, folded per-head K LayerNorm, DOUBLE-BUFFERED KV with
// async-STAGE split (T14): tile t+1's K/V global loads are issued into
// registers at the top of tile t, the full compute of tile t hides the HBM
// latency, then commit (wait + LDS write) lands after the compute barrier.
// LN coefficients live in a small LDS table (saves 48 VGPRs; broadcast reads).
// One block per (h=blockIdx.x, b=blockIdx.y), 4 waves.
// ---------------------------------------------------------------------------
__global__ __launch_bounds__(256) void attn_mfma(
    const u16* __restrict__ Q, const u16* __restrict__ Kb,
    const u16* __restrict__ Vb, u16* __restrict__ Res,
    const float* __restrict__ kwp, const float* __restrict__ kbp)
{
  __shared__ __align__(16) u16 Ks[2][64 * 104];
  __shared__ __align__(16) u16 Vt[2][96 * 72];
  __shared__ __align__(16) u16 Ps[4][16 * 72];
  __shared__ float kwb[96], kbb[96];
  const int h = blockIdx.x, b = blockIdx.y;
  const int t = threadIdx.x, lane = t & 63, wv = t >> 6;
  const int quad = lane >> 4, rsel = lane & 15;

  if (t < 96) { kwb[t] = kwp[t]; kbb[t] = kbp[t]; }

  bf16x8 aq[3];
  const int qrow0 = b * 64 + wv * 16;
  {
    const u16* qp = Q + (size_t)(qrow0 + rsel) * 1536 + h * 96 + quad * 8;
    aq[0] = *(const bf16x8*)(qp);
    aq[1] = *(const bf16x8*)(qp + 32);
    aq[2] = *(const bf16x8*)(qp + 64);
  }

  f32x4 accO[6] = {};
  float mrow[4] = {-1e30f, -1e30f, -1e30f, -1e30f};
  float lrow[4] = {0.f, 0.f, 0.f, 0.f};

  const size_t kvbase = (size_t)b * 2112 * 1536 + (size_t)h * 96;
  u16* ps = Ps[wv];

  // staging registers (static-indexed; rule #20)
  u16x8 kreg[3];
  ushort4 vreg[3][2];

  auto issue = [&](int tile) {
#pragma unroll
    for (int it = 0; it < 3; ++it) {
      const int e0 = (((wv * 3 + it) << 6) + lane) << 3;
      const int j = e0 / 96, d = e0 - j * 96;
      kreg[it] = *(const u16x8*)(Kb + kvbase + (size_t)(tile * 64 + j) * 1536 + d);
    }
#pragma unroll
    for (int it = 0; it < 3; ++it) {
      const int g = ((wv * 3 + it) << 6) + lane;
      const int kvp = g & 31, dr = g >> 5;
      const size_t ga = kvbase + (size_t)(tile * 64 + kvp * 2) * 1536 + dr * 4;
      vreg[it][0] = *(const ushort4*)(Vb + ga);
      vreg[it][1] = *(const ushort4*)(Vb + ga + 1536);
    }
  };
  auto commit = [&](int bufi) {
#pragma unroll
    for (int it = 0; it < 3; ++it) {
      const int e0 = (((wv * 3 + it) << 6) + lane) << 3;
      const int j = e0 / 96, d = e0 - j * 96;
      *(u16x8*)(Ks[bufi] + j * 104 + d) = kreg[it];
    }
#pragma unroll
    for (int it = 0; it < 3; ++it) {
      const int g = ((wv * 3 + it) << 6) + lane;
      const int kvp = g & 31, dr = g >> 5;
      const ushort4 va = vreg[it][0], vb4 = vreg[it][1];
      u32* vt = (u32*)Vt[bufi];
      vt[(dr * 4 + 0) * 36 + kvp] = (u32)va.x | ((u32)vb4.x << 16);
      vt[(dr * 4 + 1) * 36 + kvp] = (u32)va.y | ((u32)vb4.y << 16);
      vt[(dr * 4 + 2) * 36 + kvp] = (u32)va.z | ((u32)vb4.z << 16);
      vt[(dr * 4 + 3) * 36 + kvp] = (u32)va.w | ((u32)vb4.w << 16);
    }
  };

  issue(0);
  commit(0);            // compiler inserts the vmcnt waits on the reg deps
  __syncthreads();

  for (int tile = 0; tile < 33; ++tile) {
    const int cur = tile & 1;
    if (tile + 1 < 33) {
      issue(tile + 1);
      __builtin_amdgcn_sched_barrier(0);   // pin loads before the compute phase
    }

    // ---- folded K head-LN on Ks[cur]: row = wv*16+rsel, cols by quad ----
    {
      const int r = (wv << 4) + rsel;
      u16* kr = Ks[cur] + r * 104 + quad * 24;
      float x[24];
#pragma unroll
      for (int j = 0; j < 6; ++j) {
        const ushort4 raw = *(const ushort4*)(kr + j * 4);
        x[j * 4 + 0] = bf2f(raw.x); x[j * 4 + 1] = bf2f(raw.y);
        x[j * 4 + 2] = bf2f(raw.z); x[j * 4 + 3] = bf2f(raw.w);
      }
      float s = 0.f, ss = 0.f;
#pragma unroll
      for (int j = 0; j < 24; ++j) { s += x[j]; ss += x[j] * x[j]; }
      s += __shfl_xor(s, 16); ss += __shfl_xor(ss, 16);
      s += __shfl_xor(s, 32); ss += __shfl_xor(ss, 32);
      const float mean = s * (1.f / 96.f);
      const float rstd = rsqrtf(ss * (1.f / 96.f) - mean * mean + 1e-5f);
#pragma unroll
      for (int j = 0; j < 6; ++j) {
        const float4 w4 = *(const float4*)(kwb + quad * 24 + j * 4);
        const float4 b4 = *(const float4*)(kbb + quad * 24 + j * 4);
        ushort4 o;
        o.x = f2bf((x[j * 4 + 0] - mean) * rstd * w4.x + b4.x);
        o.y = f2bf((x[j * 4 + 1] - mean) * rstd * w4.y + b4.y);
        o.z = f2bf((x[j * 4 + 2] - mean) * rstd * w4.z + b4.z);
        o.w = f2bf((x[j * 4 + 3] - mean) * rstd * w4.w + b4.w);
        *(ushort4*)(kr + j * 4) = o;
      }
    }
    __syncthreads();

    // ---- S = Q * K^T ----
    f32x4 accS[4] = {};
#pragma unroll
    for (int nt = 0; nt < 4; ++nt) {
#pragma unroll
      for (int kt = 0; kt < 3; ++kt) {
        const bf16x8 bk = *(const bf16x8*)(Ks[cur] + (nt * 16 + rsel) * 104 + kt * 32 + quad * 8);
        accS[nt] = __builtin_amdgcn_mfma_f32_16x16x32_bf16(aq[kt], bk, accS[nt], 0, 0, 0);
      }
    }

    // ---- online softmax ----
    float alpha[4], rs[4];
#pragma unroll
    for (int r = 0; r < 4; ++r) {
      float mt = fmaxf(fmaxf(accS[0][r], accS[1][r]), fmaxf(accS[2][r], accS[3][r]));
      mt = fmaxf(mt, __shfl_xor(mt, 1));
      mt = fmaxf(mt, __shfl_xor(mt, 2));
      mt = fmaxf(mt, __shfl_xor(mt, 4));
      mt = fmaxf(mt, __shfl_xor(mt, 8));
      const float nm = fmaxf(mrow[r], mt);
      alpha[r] = __expf(mrow[r] - nm);
      mrow[r] = nm;
      rs[r] = 0.f;
    }
#pragma unroll
    for (int nt = 0; nt < 4; ++nt)
#pragma unroll
      for (int r = 0; r < 4; ++r) {
        const float p = __expf(accS[nt][r] - mrow[r]);
        accS[nt][r] = p;
        rs[r] += p;
      }
#pragma unroll
    for (int r = 0; r < 4; ++r) {
      rs[r] += __shfl_xor(rs[r], 1);
      rs[r] += __shfl_xor(rs[r], 2);
      rs[r] += __shfl_xor(rs[r], 4);
      rs[r] += __shfl_xor(rs[r], 8);
      lrow[r] = lrow[r] * alpha[r] + rs[r];
    }
#pragma unroll
    for (int nd = 0; nd < 6; ++nd)
#pragma unroll
      for (int r = 0; r < 4; ++r) accO[nd][r] *= alpha[r];

#pragma unroll
    for (int nt = 0; nt < 4; ++nt)
#pragma unroll
      for (int r = 0; r < 4; ++r)
        ps[(quad * 4 + r) * 72 + nt * 16 + rsel] = f2bf(accS[nt][r]);

#pragma unroll
    for (int kt = 0; kt < 2; ++kt) {
      const bf16x8 ap = *(const bf16x8*)(ps + rsel * 72 + kt * 32 + quad * 8);
#pragma unroll
      for (int nd = 0; nd < 6; ++nd) {
        const bf16x8 bv = *(const bf16x8*)(Vt[cur] + (nd * 16 + rsel) * 72 + kt * 32 + quad * 8);
        accO[nd] = __builtin_amdgcn_mfma_f32_16x16x32_bf16(ap, bv, accO[nd], 0, 0, 0);
      }
    }

    if (tile + 1 < 33) commit(cur ^ 1);
    __syncthreads();
  }

  float il[4];
#pragma unroll
  for (int r = 0; r < 4; ++r) il[r] = 1.f / lrow[r];
#pragma unroll
  for (int nd = 0; nd < 6; ++nd)
#pragma unroll
    for (int r = 0; r < 4; ++r)
      Res[(size_t)(qrow0 + quad * 4 + r) * 1536 + h * 96 + nd * 16 + rsel] =
          f2bf(accO[nd][r] * il[r]);
}

// ---------------------------------------------------------------------------
extern "C" void kernel_launch(void* const* d_in, const int* in_sizes, int n_in,
                              void* d_out, int out_size, void* d_ws, size_t ws_size,
                              hipStream_t stream) {
  const float* context  = (const float*)d_in[0];
  const float* latents  = (const float*)d_in[1];
  const float* ctx_ln_w = (const float*)d_in[2];
  const float* ctx_ln_b = (const float*)d_in[3];
  const float* lat_ln_w = (const float*)d_in[4];
  const float* lat_ln_b = (const float*)d_in[5];
  const float* q_ln_w   = (const float*)d_in[6];
  const float* q_ln_b   = (const float*)d_in[7];
  const float* k_ln_w   = (const float*)d_in[8];
  const float* k_ln_b   = (const float*)d_in[9];
  const float* wq       = (const float*)d_in[10];
  const float* wk       = (const float*)d_in[11];
  const float* wv       = (const float*)d_in[12];
  const float* wo       = (const float*)d_in[13];
  const float* mlp_ln_w = (const float*)d_in[14];
  const float* mlp_ln_b = (const float*)d_in[15];
  const float* w_fc     = (const float*)d_in[16];
  const float* w_cproj  = (const float*)d_in[17];
  const float* fin_w    = (const float*)d_in[18];
  const float* fin_b    = (const float*)d_in[19];

  char* ws = (char*)d_ws;
  u16*   normctx = (u16*)(ws + 0ull);            // [65536,1280] bf16
  u16*   Kbuf    = (u16*)(ws + 167772160ull);    // [32,2112,1536] bf16
  u16*   Vbuf    = (u16*)(ws + 375390208ull);    // [32,2112,1536] bf16
  float* lat     = (float*)(ws + 583008256ull);  // [2048,1280] f32
  u16*   latn    = (u16*)(ws + 593494016ull);    // [2048,1280] bf16
  u16*   mlpn    = (u16*)(ws + 598736896ull);    // [2048,1280] bf16
  u16*   qb      = (u16*)(ws + 603979776ull);    // [2048,1536] bf16
  u16*   res     = (u16*)(ws + 610271232ull);    // [2048,1536] bf16
  u16*   hb      = (u16*)(ws + 616562688ull);    // [2048,5120] bf16
  u16*   wT      = (u16*)(ws + 637534208ull);    // transposed weights
  float* biaskv  = (float*)(ws + 687341568ull);  // [3072]

  u16* wqT   = wT;                   // [1536,1280]
  u16* wkvT  = wT + 1966080;         // [3072,1280] (k then v, unfolded)
  u16* wkvfT = wT + 5898240;         // [3072,1280] (k then v, ctx_ln_w folded)
  u16* woT   = wT + 9830400;         // [1280,1536]
  u16* wfcT  = wT + 11796480;        // [5120,1280]
  u16* wcpT  = wT + 18350080;        // [1280,5120]

  const float qscale = 1.0f / sqrtf(96.0f);

  ln_rows<u16><<<65536, 320, 0, stream>>>(context, normctx, nullptr, nullptr);
  lat_init<<<2048, 320, 0, stream>>>(latents, lat);

  for (int i = 0; i < 3; ++i) {
    transcast<<<dim3(48, 40), 256, 0, stream>>>(wq + (size_t)i * 1966080, wqT, nullptr, 1280, 1536);
    transcast<<<dim3(48, 40), 256, 0, stream>>>(wk + (size_t)i * 1966080, wkvT, nullptr, 1280, 1536);
    transcast<<<dim3(48, 40), 256, 0, stream>>>(wv + (size_t)i * 1966080, wkvT + 1966080, nullptr, 1280, 1536);
    transcast<<<dim3(48, 40), 256, 0, stream>>>(wk + (size_t)i * 1966080, wkvfT, ctx_ln_w + i * 1280, 1280, 1536);
    transcast<<<dim3(48, 40), 256, 0, stream>>>(wv + (size_t)i * 1966080, wkvfT + 1966080, ctx_ln_w + i * 1280, 1280, 1536);
    transcast<<<dim3(40, 48), 256, 0, stream>>>(wo + (size_t)i * 1966080, woT, nullptr, 1536, 1280);
    transcast<<<dim3(160, 40), 256, 0, stream>>>(w_fc + (size_t)i * 6553600, wfcT, nullptr, 1280, 5120);
    transcast<<<dim3(40, 160), 256, 0, stream>>>(w_cproj + (size_t)i * 6553600, wcpT, nullptr, 5120, 1280);
    bias_dot<<<3072, 64, 0, stream>>>(wkvT, ctx_ln_b + i * 1280, biaskv, 1280);

    ln_rows<u16><<<2048, 320, 0, stream>>>(lat, latn, lat_ln_w + i * 1280, lat_ln_b + i * 1280);

    // ctx K/V fused: 256x256 8-phase kernel. grid = 256*12 = 3072 (%8==0).
    gemm_kv256<<<3072, 512, 0, stream>>>(normctx, wkvfT, Kbuf, Vbuf, biaskv,
        1280, 1536, 11, 2112, 0, 12);
    // latent K/V rows
    gemm_bf16<4><<<dim3(24, 16), 256, 0, stream>>>(latn, wkvT, Kbuf, Vbuf, nullptr, nullptr,
        2048, 3072, 1536, 1280, 6, 2112, 2048, 1 | 4);
    // Q (128x64 tiles -> 384 blocks)
    gemm_bf16<2><<<dim3(24, 16), 256, 0, stream>>>(latn, wqT, qb, nullptr, nullptr, nullptr,
        2048, 1536, 1536, 1280, 11, 2048, 0, 1);

    // per-head LN on q (qk_scale folded); K-LN is folded into attn staging.
    seg_ln<<<8192, 256, 0, stream>>>(qb, q_ln_w + i * 96, q_ln_b + i * 96, qscale, 32768);

    attn_mfma<<<dim3(16, 32), 256, 0, stream>>>(qb, Kbuf, Vbuf, res,
        k_ln_w + i * 96, k_ln_b + i * 96);

    // lat = res @ wo + lat  (128x64 tiles -> 320 blocks)
    gemm_bf16<2><<<dim3(20, 16), 256, 0, stream>>>(res, woT, lat, nullptr, nullptr, lat,
        2048, 1280, 1280, 1536, 11, 2048, 0, 0);

    // MLP
    ln_rows<u16><<<2048, 320, 0, stream>>>(lat, mlpn, mlp_ln_w + i * 1280, mlp_ln_b + i * 1280);
    gemm_bf16<4><<<dim3(40, 16), 256, 0, stream>>>(mlpn, wfcT, hb, nullptr, nullptr, nullptr,
        2048, 5120, 5120, 1280, 11, 2048, 0, 1 | 2);
    gemm_bf16<2><<<dim3(20, 16), 256, 0, stream>>>(hb, wcpT, lat, nullptr, nullptr, lat,
        2048, 1280, 1280, 5120, 11, 2048, 0, 0);
  }

  ln_rows<float><<<2048, 320, 0, stream>>>(lat, (float*)d_out, fin_w, fin_b);
}